// Round 13
// baseline (131.696 us; speedup 1.0000x reference)
//
#include <hip/hip_runtime.h>
#include <hip/hip_bf16.h>
#include <math.h>

// Problem constants (from reference): B=4, S=2048, E=512, H=8, DK=64
#define B_ 4
#define S_ 2048
#define E_ 512
#define H_ 8
#define DK_ 64

typedef __attribute__((ext_vector_type(8))) short short8;    // 8x16b (4 VGPRs)
typedef __attribute__((ext_vector_type(4))) float f32x4;     // MFMA C/D frag
typedef _Float16 half8 __attribute__((ext_vector_type(8)));  // 8 f16
typedef _Float16 half4 __attribute__((ext_vector_type(4)));  // 4 f16
typedef __fp16 fp16x2 __attribute__((ext_vector_type(2)));   // cvt_pkrtz result
typedef unsigned uint4v __attribute__((ext_vector_type(4)));

__device__ inline short8 ld8(const void* p) {
  return *reinterpret_cast<const short8*>(p);
}
__device__ inline half8 ld8h(const void* p) {
  return *reinterpret_cast<const half8*>(p);
}

static __device__ inline unsigned pk2(float a, float b) {
  fp16x2 h = __builtin_amdgcn_cvt_pkrtz(a, b);  // v_cvt_pkrtz_f16_f32
  return __builtin_bit_cast(unsigned, h);
}
static __device__ inline half8 pack8(float p0, float p1, float p2, float p3,
                                     float p4, float p5, float p6, float p7) {
  uint4v u;
  u[0] = pk2(p0, p1); u[1] = pk2(p2, p3);
  u[2] = pk2(p4, p5); u[3] = pk2(p6, p7);
  return __builtin_bit_cast(half8, u);
}

// ---------------------------------------------------------------------------
// Fragment-order layouts (R8/R9): kA = QK A/B-operand order with the key
// permutation that makes QK C-tiles concatenate into the PV K=32 B-operand;
// vA = V^T A-operand order. Waves load frags as coalesced 1KB dwordx4. No
// LDS, no barriers in the attention K-loop.
// ---------------------------------------------------------------------------

// ---------------------------------------------------------------------------
// Kernel 1: cos(x+theta) -> kA (frag order, serves Q and K) + vA (frag order).
// ---------------------------------------------------------------------------
__global__ __launch_bounds__(256) void prep_g_kernel(
    const float* __restrict__ x, const float* __restrict__ theta,
    _Float16* __restrict__ kA, _Float16* __restrict__ vA) {
  const int bh = blockIdx.y;
  const int b = bh >> 3, h = bh & 7;
  const int s0 = blockIdx.x * 64;
  const int tid = threadIdx.x;
  const int wave = tid >> 6, lane = tid & 63;
  const int col = lane & 15, quad = lane >> 4;
  __shared__ _Float16 tile[64 * 72];

  const float* xp = x + ((size_t)(b * S_ + s0)) * E_ + h * DK_;
#pragma unroll
  for (int it = 0; it < 16; ++it) {
    int idx = it * 256 + tid;
    int sr = idx >> 6, dc = idx & 63;
    tile[sr * 72 + dc] = (_Float16)__cosf(xp[(size_t)sr * E_ + dc] + theta[dc]);
  }
  __syncthreads();

  _Float16* kb = kA + (size_t)bh * (S_ * DK_);
  _Float16* vb = vA + (size_t)bh * (S_ * DK_);
  const int Gbase = s0 >> 5;
  // kA: 8 chunks (2 Gl x 2 g x 2 hh); wave handles chunk wave + it2*4
#pragma unroll
  for (int it2 = 0; it2 < 2; ++it2) {
    int c = wave + it2 * 4;
    int Gl = c >> 2, g = (c >> 1) & 1, hh = c & 1;
    int ploc = Gl * 32 + ((col >> 2) << 3) + g * 4 + (col & 3);
    half8 v = ld8h(tile + ploc * 72 + hh * 32 + quad * 8);
    *reinterpret_cast<half8*>(
        kb + ((size_t)(Gbase + Gl) * 2048 + (g * 2 + hh) * 512 + lane * 8)) = v;
  }
  // vA: 8 chunks (2 Gl x 4 dcc); transposed gather from tile
#pragma unroll
  for (int it2 = 0; it2 < 2; ++it2) {
    int c = wave + it2 * 4;
    int Gl = c >> 2, dcc = c & 3;
    half8 v;
#pragma unroll
    for (int j = 0; j < 8; ++j)
      v[j] = tile[(Gl * 32 + quad * 8 + j) * 72 + dcc * 16 + col];
    *reinterpret_cast<half8*>(
        vb + ((size_t)(Gbase + Gl) * 2048 + dcc * 512 + lane * 8)) = v;
  }
}

// ---------------------------------------------------------------------------
// Kernel 2: W (fp32) -> f16
// ---------------------------------------------------------------------------
__global__ void prep_w_kernel(const float* __restrict__ W, _Float16* __restrict__ wb) {
  int i = (blockIdx.x * 256 + threadIdx.x) * 8;
  float4 a = *reinterpret_cast<const float4*>(W + i);
  float4 c = *reinterpret_cast<const float4*>(W + i + 4);
  half8 v;
  v[0]=(_Float16)a.x; v[1]=(_Float16)a.y; v[2]=(_Float16)a.z; v[3]=(_Float16)a.w;
  v[4]=(_Float16)c.x; v[5]=(_Float16)c.y; v[6]=(_Float16)c.z; v[7]=(_Float16)c.w;
  *reinterpret_cast<half8*>(wb + i) = v;
}

// ---------------------------------------------------------------------------
// Kernel 3: attention — barrier-free LDS-free K-loop + XCD swizzle (R12) +
// 32-ROW Q-BLOCKS: grid 2048 = 8 blocks/CU (was 4; OccupancyPercent was 22%,
// grid-capped). qa/o register footprint halves (~60 VGPR) -> ~8 waves/SIMD
// of phase diversity for the QK->exp2->PV chain. K/V L2 traffic doubles but
// stays XCD-local (2 MB/XCD). No min-waves pledge (R10 lesson).
// ---------------------------------------------------------------------------
__global__ __launch_bounds__(256) void attn_kernel(
    const _Float16* __restrict__ kA, const _Float16* __restrict__ vA,
    _Float16* __restrict__ ao) {
  const int tid = threadIdx.x;
  const int wave = tid >> 6, lane = tid & 63;
  const int col = lane & 15, quad = lane >> 4;
  // swizzle: 2048 wgs; XCD x owns bh [4x,4x+4)
  const int wg = blockIdx.x + 64 * blockIdx.y;
  const int xcd = wg & 7, slot = wg >> 3;
  const int bh = xcd * 4 + (slot >> 6);
  const int q0 = (slot & 63) * 32;
  const _Float16* kb = kA + (size_t)bh * (S_ * DK_);
  const _Float16* vb = vA + (size_t)bh * (S_ * DK_);

  // Q frags: single 32-group (q0>>5), qc = g in {0,1}; scaled by C1
  const _Float16 hC1 = (_Float16)0.18033688011112042f;  // 0.125*log2(e)
  half8 qa[2][2];
#pragma unroll
  for (int qc = 0; qc < 2; ++qc)
#pragma unroll
    for (int hh = 0; hh < 2; ++hh)
      qa[qc][hh] = ld8h(kb + (size_t)(q0 >> 5) * 2048 +
                        (qc * 2 + hh) * 512 + lane * 8) * hC1;

  f32x4 o[2][4];
#pragma unroll
  for (int qc = 0; qc < 2; ++qc)
#pragma unroll
    for (int dc = 0; dc < 4; ++dc) o[qc][dc] = f32x4{0.f, 0.f, 0.f, 0.f};
  float l[2] = {0.f, 0.f};

  const _Float16* kw = kb + (size_t)wave * 16 * 2048 + lane * 8;
  const _Float16* vw = vb + (size_t)wave * 16 * 2048 + lane * 8;

  for (int it = 0; it < 16; ++it) {
    const _Float16* kit = kw + it * 2048;
    const _Float16* vit = vw + it * 2048;
    half8 kf00 = ld8h(kit);
    half8 kf01 = ld8h(kit + 512);
    half8 kf10 = ld8h(kit + 1024);
    half8 kf11 = ld8h(kit + 1536);
    half8 vf0 = ld8h(vit);
    half8 vf1 = ld8h(vit + 512);
    half8 vf2 = ld8h(vit + 1024);
    half8 vf3 = ld8h(vit + 1536);

    half8 pf[2];
#pragma unroll
    for (int qc = 0; qc < 2; ++qc) {
      f32x4 z0{0.f, 0.f, 0.f, 0.f}, z1{0.f, 0.f, 0.f, 0.f};
      z0 = __builtin_amdgcn_mfma_f32_16x16x32_f16(kf00, qa[qc][0], z0, 0, 0, 0);
      z0 = __builtin_amdgcn_mfma_f32_16x16x32_f16(kf01, qa[qc][1], z0, 0, 0, 0);
      z1 = __builtin_amdgcn_mfma_f32_16x16x32_f16(kf10, qa[qc][0], z1, 0, 0, 0);
      z1 = __builtin_amdgcn_mfma_f32_16x16x32_f16(kf11, qa[qc][1], z1, 0, 0, 0);
      float p0 = __builtin_amdgcn_exp2f(z0[0]);
      float p1 = __builtin_amdgcn_exp2f(z0[1]);
      float p2 = __builtin_amdgcn_exp2f(z0[2]);
      float p3 = __builtin_amdgcn_exp2f(z0[3]);
      float p4 = __builtin_amdgcn_exp2f(z1[0]);
      float p5 = __builtin_amdgcn_exp2f(z1[1]);
      float p6 = __builtin_amdgcn_exp2f(z1[2]);
      float p7 = __builtin_amdgcn_exp2f(z1[3]);
      l[qc] += ((p0 + p1) + (p2 + p3)) + ((p4 + p5) + (p6 + p7));
      pf[qc] = pack8(p0, p1, p2, p3, p4, p5, p6, p7);
    }
#pragma unroll
    for (int qc = 0; qc < 2; ++qc) {
      o[qc][0] = __builtin_amdgcn_mfma_f32_16x16x32_f16(vf0, pf[qc], o[qc][0], 0, 0, 0);
      o[qc][1] = __builtin_amdgcn_mfma_f32_16x16x32_f16(vf1, pf[qc], o[qc][1], 0, 0, 0);
      o[qc][2] = __builtin_amdgcn_mfma_f32_16x16x32_f16(vf2, pf[qc], o[qc][2], 0, 0, 0);
      o[qc][3] = __builtin_amdgcn_mfma_f32_16x16x32_f16(vf3, pf[qc], o[qc][3], 0, 0, 0);
    }
  }

  // ---- one-time cross-wave reduction (2 rounds; reducers = waves 0,1) ----
  __shared__ float reds[4096];  // 16 KB
#pragma unroll
  for (int qc = 0; qc < 2; ++qc) {
    float t = l[qc];
    t += __shfl_xor(t, 16);
    t += __shfl_xor(t, 32);
    l[qc] = t;
  }
  if (quad == 0) {
#pragma unroll
    for (int qc = 0; qc < 2; ++qc) reds[(wave * 2 + qc) * 16 + col] = l[qc];
  }
  __syncthreads();
  float ltot = 0.f;
#pragma unroll
  for (int w2 = 0; w2 < 4; ++w2) ltot += reds[(w2 * 2 + (wave & 1)) * 16 + col];
  float inv = __builtin_amdgcn_rcpf(ltot);  // valid for wave<2 (reducers)

  const int b = bh >> 3, h = bh & 7;
  // store row carries the kA q-permutation within the 32-group: g = qc
  _Float16* op_base = ao + ((size_t)b * S_) * E_ + h * DK_;
#pragma unroll
  for (int qc = 0; qc < 2; ++qc) {
    __syncthreads();
#pragma unroll
    for (int dc = 0; dc < 4; ++dc)
      *reinterpret_cast<f32x4*>(reds + wave * 1024 + lane * 16 + dc * 4) = o[qc][dc];
    __syncthreads();
    if (wave == qc) {
      const int qrow = q0 + ((col >> 2) << 3) + qc * 4 + (col & 3);
      _Float16* op = op_base + (size_t)qrow * E_;
#pragma unroll
      for (int dc = 0; dc < 4; ++dc) {
        f32x4 acc = *reinterpret_cast<const f32x4*>(reds + lane * 16 + dc * 4);
#pragma unroll
        for (int w2 = 1; w2 < 4; ++w2)
          acc = acc + *reinterpret_cast<const f32x4*>(reds + w2 * 1024 + lane * 16 + dc * 4);
        half4 pk4;
        pk4[0] = (_Float16)(acc[0] * inv);
        pk4[1] = (_Float16)(acc[1] * inv);
        pk4[2] = (_Float16)(acc[2] * inv);
        pk4[3] = (_Float16)(acc[3] * inv);
        *reinterpret_cast<half4*>(op + dc * 16 + quad * 4) = pk4;
      }
    }
  }
}

// ---------------------------------------------------------------------------
// Kernel 4: out = attnout @ W^T + b  (M=8192, N=512, K=512), fp32 out.
// LDS-staged, BK=128, pre-converted wb f16.
// ---------------------------------------------------------------------------
__global__ __launch_bounds__(256) void proj_kernel(
    const _Float16* __restrict__ ao, const _Float16* __restrict__ wb,
    const float* __restrict__ bias, float* __restrict__ out) {
  const int tid = threadIdx.x;
  const int wave = tid >> 6, lane = tid & 63;
  const int col = lane & 15, quad = lane >> 4;
  const int m0 = blockIdx.x * 64;
  const int n0 = blockIdx.y * 64;
  __shared__ short at[64 * 136];
  __shared__ short bt[64 * 136];

  const int srw = tid >> 4;        // 0..15
  const int soff = (tid & 15) * 8; // 0..120

  short8 ap_[4], wp_[4];
#pragma unroll
  for (int it = 0; it < 4; ++it) {
    int row = it * 16 + srw;
    ap_[it] = ld8(ao + (size_t)(m0 + row) * E_ + soff);
    wp_[it] = ld8(wb + (size_t)(n0 + row) * E_ + soff);
  }

  f32x4 acc[4] = {{0.f,0.f,0.f,0.f},{0.f,0.f,0.f,0.f},{0.f,0.f,0.f,0.f},{0.f,0.f,0.f,0.f}};

  for (int k0 = 0; k0 < E_; k0 += 128) {
#pragma unroll
    for (int it = 0; it < 4; ++it) {
      int row = it * 16 + srw;
      *reinterpret_cast<short8*>(at + row * 136 + soff) = ap_[it];
      *reinterpret_cast<short8*>(bt + row * 136 + soff) = wp_[it];
    }
    __syncthreads();
    if (k0 + 128 < E_) {
#pragma unroll
      for (int it = 0; it < 4; ++it) {
        int row = it * 16 + srw;
        ap_[it] = ld8(ao + (size_t)(m0 + row) * E_ + k0 + 128 + soff);
        wp_[it] = ld8(wb + (size_t)(n0 + row) * E_ + k0 + 128 + soff);
      }
    }
#pragma unroll
    for (int ks = 0; ks < 4; ++ks) {
      half8 a = *reinterpret_cast<const half8*>(at + (wave * 16 + col) * 136 + ks * 32 + quad * 8);
#pragma unroll
      for (int f = 0; f < 4; ++f) {
        half8 bb = *reinterpret_cast<const half8*>(bt + (f * 16 + col) * 136 + ks * 32 + quad * 8);
        acc[f] = __builtin_amdgcn_mfma_f32_16x16x32_f16(a, bb, acc[f], 0, 0, 0);
      }
    }
    __syncthreads();
  }

#pragma unroll
  for (int f = 0; f < 4; ++f) {
    float bv = bias[n0 + f * 16 + col];
#pragma unroll
    for (int r = 0; r < 4; ++r) {
      int row = m0 + wave * 16 + quad * 4 + r;
      out[(size_t)row * E_ + n0 + f * 16 + col] = acc[f][r] + bv;
    }
  }
}

// ---------------------------------------------------------------------------
// ws layout (~25.1 MB):
//   [0)        kA  f16 frag-order [B*H][64G][4][512]   8388608 B
//   [8388608)  vA  f16 frag-order                      8388608 B
//   [16777216) ao  f16 [B,S,E]                         8388608 B
//   [25165824) wb  f16 [E,E]                            524288 B
// ---------------------------------------------------------------------------
extern "C" void kernel_launch(void* const* d_in, const int* in_sizes, int n_in,
                              void* d_out, int out_size, void* d_ws, size_t ws_size,
                              hipStream_t stream) {
  const float* x = (const float*)d_in[0];
  const float* theta = (const float*)d_in[1];
  const float* W = (const float*)d_in[2];
  const float* bias = (const float*)d_in[3];
  float* out = (float*)d_out;
  char* ws = (char*)d_ws;
  const size_t gsz = (size_t)B_ * H_ * S_ * DK_ * 2;  // 8388608
  _Float16* kA = (_Float16*)ws;
  _Float16* vA = (_Float16*)(ws + gsz);
  _Float16* ao = (_Float16*)(ws + 2 * gsz);
  _Float16* wb = (_Float16*)(ws + 3 * gsz);

  prep_g_kernel<<<dim3(S_ / 64, B_ * H_), 256, 0, stream>>>(x, theta, kA, vA);
  prep_w_kernel<<<dim3((E_ * E_) / (256 * 8)), 256, 0, stream>>>(W, wb);
  attn_kernel<<<dim3(S_ / 32, B_ * H_), 256, 0, stream>>>(kA, vA, ao);
  proj_kernel<<<dim3((B_ * S_) / 64, E_ / 64), 256, 0, stream>>>(ao, wb, bias, out);
}

// Round 14
// 124.133 us; speedup vs baseline: 1.0609x; 1.0609x over previous
//
#include <hip/hip_runtime.h>
#include <hip/hip_bf16.h>
#include <math.h>

// Problem constants (from reference): B=4, S=2048, E=512, H=8, DK=64
#define B_ 4
#define S_ 2048
#define E_ 512
#define H_ 8
#define DK_ 64

typedef __attribute__((ext_vector_type(8))) short short8;    // 8x16b (4 VGPRs)
typedef __attribute__((ext_vector_type(4))) float f32x4;     // MFMA C/D frag
typedef _Float16 half8 __attribute__((ext_vector_type(8)));  // 8 f16
typedef _Float16 half4 __attribute__((ext_vector_type(4)));  // 4 f16
typedef __fp16 fp16x2 __attribute__((ext_vector_type(2)));   // cvt_pkrtz result
typedef unsigned uint4v __attribute__((ext_vector_type(4)));

__device__ inline short8 ld8(const void* p) {
  return *reinterpret_cast<const short8*>(p);
}
__device__ inline half8 ld8h(const void* p) {
  return *reinterpret_cast<const half8*>(p);
}

static __device__ inline unsigned pk2(float a, float b) {
  fp16x2 h = __builtin_amdgcn_cvt_pkrtz(a, b);  // v_cvt_pkrtz_f16_f32
  return __builtin_bit_cast(unsigned, h);
}
static __device__ inline half8 pack8(float p0, float p1, float p2, float p3,
                                     float p4, float p5, float p6, float p7) {
  uint4v u;
  u[0] = pk2(p0, p1); u[1] = pk2(p2, p3);
  u[2] = pk2(p4, p5); u[3] = pk2(p6, p7);
  return __builtin_bit_cast(half8, u);
}

// ---------------------------------------------------------------------------
// Fragment-order layouts (R8/R9): kA = QK A/B-operand order with the key
// permutation that makes QK C-tiles concatenate into the PV K=32 B-operand;
// vA = V^T A-operand order. Waves load frags as coalesced 1KB dwordx4. No
// LDS, no barriers in the attention K-loop.
// R13 LESSON: 32-row q-blocks double per-MFMA load overhead (-7 us); 64-row
// blocks (R12) are the operating point.
// ---------------------------------------------------------------------------

// ---------------------------------------------------------------------------
// Kernel 1: cos(x+theta) -> kA (frag order, serves Q and K) + vA (frag order).
// ---------------------------------------------------------------------------
__global__ __launch_bounds__(256) void prep_g_kernel(
    const float* __restrict__ x, const float* __restrict__ theta,
    _Float16* __restrict__ kA, _Float16* __restrict__ vA) {
  const int bh = blockIdx.y;
  const int b = bh >> 3, h = bh & 7;
  const int s0 = blockIdx.x * 64;
  const int tid = threadIdx.x;
  const int wave = tid >> 6, lane = tid & 63;
  const int col = lane & 15, quad = lane >> 4;
  __shared__ _Float16 tile[64 * 72];

  const float* xp = x + ((size_t)(b * S_ + s0)) * E_ + h * DK_;
#pragma unroll
  for (int it = 0; it < 16; ++it) {
    int idx = it * 256 + tid;
    int sr = idx >> 6, dc = idx & 63;
    tile[sr * 72 + dc] = (_Float16)__cosf(xp[(size_t)sr * E_ + dc] + theta[dc]);
  }
  __syncthreads();

  _Float16* kb = kA + (size_t)bh * (S_ * DK_);
  _Float16* vb = vA + (size_t)bh * (S_ * DK_);
  const int Gbase = s0 >> 5;
  // kA: 8 chunks (2 Gl x 2 g x 2 hh); wave handles chunk wave + it2*4
#pragma unroll
  for (int it2 = 0; it2 < 2; ++it2) {
    int c = wave + it2 * 4;
    int Gl = c >> 2, g = (c >> 1) & 1, hh = c & 1;
    int ploc = Gl * 32 + ((col >> 2) << 3) + g * 4 + (col & 3);
    half8 v = ld8h(tile + ploc * 72 + hh * 32 + quad * 8);
    *reinterpret_cast<half8*>(
        kb + ((size_t)(Gbase + Gl) * 2048 + (g * 2 + hh) * 512 + lane * 8)) = v;
  }
  // vA: 8 chunks (2 Gl x 4 dcc); transposed gather from tile
#pragma unroll
  for (int it2 = 0; it2 < 2; ++it2) {
    int c = wave + it2 * 4;
    int Gl = c >> 2, dcc = c & 3;
    half8 v;
#pragma unroll
    for (int j = 0; j < 8; ++j)
      v[j] = tile[(Gl * 32 + quad * 8 + j) * 72 + dcc * 16 + col];
    *reinterpret_cast<half8*>(
        vb + ((size_t)(Gbase + Gl) * 2048 + dcc * 512 + lane * 8)) = v;
  }
}

// ---------------------------------------------------------------------------
// Kernel 2: W (fp32) -> f16
// ---------------------------------------------------------------------------
__global__ void prep_w_kernel(const float* __restrict__ W, _Float16* __restrict__ wb) {
  int i = (blockIdx.x * 256 + threadIdx.x) * 8;
  float4 a = *reinterpret_cast<const float4*>(W + i);
  float4 c = *reinterpret_cast<const float4*>(W + i + 4);
  half8 v;
  v[0]=(_Float16)a.x; v[1]=(_Float16)a.y; v[2]=(_Float16)a.z; v[3]=(_Float16)a.w;
  v[4]=(_Float16)c.x; v[5]=(_Float16)c.y; v[6]=(_Float16)c.z; v[7]=(_Float16)c.w;
  *reinterpret_cast<half8*>(wb + i) = v;
}

// ---------------------------------------------------------------------------
// Kernel 3: attention — R12 config (best measured): barrier-free LDS-free
// K-loop, 64 q-rows/block, XCD swizzle (XCD x owns bh [4x,4x+4): kA+vA
// footprint 2 MB/XCD, L2-resident, FETCH ~= working set).
// ---------------------------------------------------------------------------
__global__ __launch_bounds__(256, 3) void attn_kernel(
    const _Float16* __restrict__ kA, const _Float16* __restrict__ vA,
    _Float16* __restrict__ ao) {
  const int tid = threadIdx.x;
  const int wave = tid >> 6, lane = tid & 63;
  const int col = lane & 15, quad = lane >> 4;
  const int wg = blockIdx.x + 32 * blockIdx.y;
  const int xcd = wg & 7, slot = wg >> 3;
  const int bh = xcd * 4 + (slot >> 5);
  const int q0 = (slot & 31) * 64;
  const _Float16* kb = kA + (size_t)bh * (S_ * DK_);
  const _Float16* vb = vA + (size_t)bh * (S_ * DK_);

  // Q frags: qc=(Gq,g): chunk ((q0>>5)+Gq, g, h), scaled by C1
  const _Float16 hC1 = (_Float16)0.18033688011112042f;  // 0.125*log2(e)
  half8 qa[4][2];
#pragma unroll
  for (int qc = 0; qc < 4; ++qc)
#pragma unroll
    for (int hh = 0; hh < 2; ++hh)
      qa[qc][hh] = ld8h(kb + (size_t)((q0 >> 5) + (qc >> 1)) * 2048 +
                        ((qc & 1) * 2 + hh) * 512 + lane * 8) * hC1;

  f32x4 o[4][4];
#pragma unroll
  for (int qc = 0; qc < 4; ++qc)
#pragma unroll
    for (int dc = 0; dc < 4; ++dc) o[qc][dc] = f32x4{0.f, 0.f, 0.f, 0.f};
  float l[4] = {0.f, 0.f, 0.f, 0.f};

  const _Float16* kw = kb + (size_t)wave * 16 * 2048 + lane * 8;
  const _Float16* vw = vb + (size_t)wave * 16 * 2048 + lane * 8;

  for (int it = 0; it < 16; ++it) {
    const _Float16* kit = kw + it * 2048;
    const _Float16* vit = vw + it * 2048;
    half8 kf00 = ld8h(kit);
    half8 kf01 = ld8h(kit + 512);
    half8 kf10 = ld8h(kit + 1024);
    half8 kf11 = ld8h(kit + 1536);
    half8 vf0 = ld8h(vit);
    half8 vf1 = ld8h(vit + 512);
    half8 vf2 = ld8h(vit + 1024);
    half8 vf3 = ld8h(vit + 1536);

    half8 pf[4];
#pragma unroll
    for (int qc = 0; qc < 4; ++qc) {
      f32x4 z0{0.f, 0.f, 0.f, 0.f}, z1{0.f, 0.f, 0.f, 0.f};
      z0 = __builtin_amdgcn_mfma_f32_16x16x32_f16(kf00, qa[qc][0], z0, 0, 0, 0);
      z0 = __builtin_amdgcn_mfma_f32_16x16x32_f16(kf01, qa[qc][1], z0, 0, 0, 0);
      z1 = __builtin_amdgcn_mfma_f32_16x16x32_f16(kf10, qa[qc][0], z1, 0, 0, 0);
      z1 = __builtin_amdgcn_mfma_f32_16x16x32_f16(kf11, qa[qc][1], z1, 0, 0, 0);
      float p0 = __builtin_amdgcn_exp2f(z0[0]);
      float p1 = __builtin_amdgcn_exp2f(z0[1]);
      float p2 = __builtin_amdgcn_exp2f(z0[2]);
      float p3 = __builtin_amdgcn_exp2f(z0[3]);
      float p4 = __builtin_amdgcn_exp2f(z1[0]);
      float p5 = __builtin_amdgcn_exp2f(z1[1]);
      float p6 = __builtin_amdgcn_exp2f(z1[2]);
      float p7 = __builtin_amdgcn_exp2f(z1[3]);
      l[qc] += ((p0 + p1) + (p2 + p3)) + ((p4 + p5) + (p6 + p7));
      pf[qc] = pack8(p0, p1, p2, p3, p4, p5, p6, p7);
    }
#pragma unroll
    for (int qc = 0; qc < 4; ++qc) {
      o[qc][0] = __builtin_amdgcn_mfma_f32_16x16x32_f16(vf0, pf[qc], o[qc][0], 0, 0, 0);
      o[qc][1] = __builtin_amdgcn_mfma_f32_16x16x32_f16(vf1, pf[qc], o[qc][1], 0, 0, 0);
      o[qc][2] = __builtin_amdgcn_mfma_f32_16x16x32_f16(vf2, pf[qc], o[qc][2], 0, 0, 0);
      o[qc][3] = __builtin_amdgcn_mfma_f32_16x16x32_f16(vf3, pf[qc], o[qc][3], 0, 0, 0);
    }
  }

  // ---- one-time cross-wave reduction (R7 scheme) ----
  __shared__ float reds[4096];  // 16 KB
#pragma unroll
  for (int qc = 0; qc < 4; ++qc) {
    float t = l[qc];
    t += __shfl_xor(t, 16);
    t += __shfl_xor(t, 32);
    l[qc] = t;
  }
  if (quad == 0) {
#pragma unroll
    for (int qc = 0; qc < 4; ++qc) reds[(wave * 4 + qc) * 16 + col] = l[qc];
  }
  __syncthreads();
  float ltot = 0.f;
#pragma unroll
  for (int w2 = 0; w2 < 4; ++w2) ltot += reds[(w2 * 4 + wave) * 16 + col];
  float inv = __builtin_amdgcn_rcpf(ltot);  // denominator for qc == wave

  const int b = bh >> 3, h = bh & 7;
  // store row carries the kA q-permutation: qc=(Gq,g), col -> q
  const int qrow = q0 + ((wave >> 1) << 5) + ((col >> 2) << 3) + (wave & 1) * 4 + (col & 3);
  _Float16* op = ao + ((size_t)b * S_ + qrow) * E_ + h * DK_;
#pragma unroll
  for (int qc = 0; qc < 4; ++qc) {
    __syncthreads();
#pragma unroll
    for (int dc = 0; dc < 4; ++dc)
      *reinterpret_cast<f32x4*>(reds + wave * 1024 + lane * 16 + dc * 4) = o[qc][dc];
    __syncthreads();
    if (wave == qc) {
#pragma unroll
      for (int dc = 0; dc < 4; ++dc) {
        f32x4 acc = *reinterpret_cast<const f32x4*>(reds + lane * 16 + dc * 4);
#pragma unroll
        for (int w2 = 1; w2 < 4; ++w2)
          acc = acc + *reinterpret_cast<const f32x4*>(reds + w2 * 1024 + lane * 16 + dc * 4);
        half4 pk4;
        pk4[0] = (_Float16)(acc[0] * inv);
        pk4[1] = (_Float16)(acc[1] * inv);
        pk4[2] = (_Float16)(acc[2] * inv);
        pk4[3] = (_Float16)(acc[3] * inv);
        *reinterpret_cast<half4*>(op + dc * 16 + quad * 4) = pk4;
      }
    }
  }
}

// ---------------------------------------------------------------------------
// Kernel 4: out = attnout @ W^T + b  (M=8192, N=512, K=512), fp32 out.
// LDS-staged, BK=128, pre-converted wb f16 + XCD SWIZZLE: XCD x owns m-tiles
// [16x,16x+16) x all 8 n-tiles -> per-XCD footprint = 1 MB ao + 0.5 MB wb
// (L2-resident; default round-robin made every XCD pull ~all of ao).
// ---------------------------------------------------------------------------
__global__ __launch_bounds__(256) void proj_kernel(
    const _Float16* __restrict__ ao, const _Float16* __restrict__ wb,
    const float* __restrict__ bias, float* __restrict__ out) {
  const int tid = threadIdx.x;
  const int wave = tid >> 6, lane = tid & 63;
  const int col = lane & 15, quad = lane >> 4;
  // swizzle: 1024 wgs = 128 m-tiles x 8 n-tiles
  const int wg = blockIdx.x + 128 * blockIdx.y;
  const int xcd = wg & 7, slot = wg >> 3;       // slot in [0,128)
  const int m0 = (xcd * 16 + (slot >> 3)) * 64;
  const int n0 = (slot & 7) * 64;
  __shared__ short at[64 * 136];
  __shared__ short bt[64 * 136];

  const int srw = tid >> 4;        // 0..15
  const int soff = (tid & 15) * 8; // 0..120

  short8 ap_[4], wp_[4];
#pragma unroll
  for (int it = 0; it < 4; ++it) {
    int row = it * 16 + srw;
    ap_[it] = ld8(ao + (size_t)(m0 + row) * E_ + soff);
    wp_[it] = ld8(wb + (size_t)(n0 + row) * E_ + soff);
  }

  f32x4 acc[4] = {{0.f,0.f,0.f,0.f},{0.f,0.f,0.f,0.f},{0.f,0.f,0.f,0.f},{0.f,0.f,0.f,0.f}};

  for (int k0 = 0; k0 < E_; k0 += 128) {
#pragma unroll
    for (int it = 0; it < 4; ++it) {
      int row = it * 16 + srw;
      *reinterpret_cast<short8*>(at + row * 136 + soff) = ap_[it];
      *reinterpret_cast<short8*>(bt + row * 136 + soff) = wp_[it];
    }
    __syncthreads();
    if (k0 + 128 < E_) {
#pragma unroll
      for (int it = 0; it < 4; ++it) {
        int row = it * 16 + srw;
        ap_[it] = ld8(ao + (size_t)(m0 + row) * E_ + k0 + 128 + soff);
        wp_[it] = ld8(wb + (size_t)(n0 + row) * E_ + k0 + 128 + soff);
      }
    }
#pragma unroll
    for (int ks = 0; ks < 4; ++ks) {
      half8 a = *reinterpret_cast<const half8*>(at + (wave * 16 + col) * 136 + ks * 32 + quad * 8);
#pragma unroll
      for (int f = 0; f < 4; ++f) {
        half8 bb = *reinterpret_cast<const half8*>(bt + (f * 16 + col) * 136 + ks * 32 + quad * 8);
        acc[f] = __builtin_amdgcn_mfma_f32_16x16x32_f16(a, bb, acc[f], 0, 0, 0);
      }
    }
    __syncthreads();
  }

#pragma unroll
  for (int f = 0; f < 4; ++f) {
    float bv = bias[n0 + f * 16 + col];
#pragma unroll
    for (int r = 0; r < 4; ++r) {
      int row = m0 + wave * 16 + quad * 4 + r;
      out[(size_t)row * E_ + n0 + f * 16 + col] = acc[f][r] + bv;
    }
  }
}

// ---------------------------------------------------------------------------
// ws layout (~25.1 MB):
//   [0)        kA  f16 frag-order [B*H][64G][4][512]   8388608 B
//   [8388608)  vA  f16 frag-order                      8388608 B
//   [16777216) ao  f16 [B,S,E]                         8388608 B
//   [25165824) wb  f16 [E,E]                            524288 B
// ---------------------------------------------------------------------------
extern "C" void kernel_launch(void* const* d_in, const int* in_sizes, int n_in,
                              void* d_out, int out_size, void* d_ws, size_t ws_size,
                              hipStream_t stream) {
  const float* x = (const float*)d_in[0];
  const float* theta = (const float*)d_in[1];
  const float* W = (const float*)d_in[2];
  const float* bias = (const float*)d_in[3];
  float* out = (float*)d_out;
  char* ws = (char*)d_ws;
  const size_t gsz = (size_t)B_ * H_ * S_ * DK_ * 2;  // 8388608
  _Float16* kA = (_Float16*)ws;
  _Float16* vA = (_Float16*)(ws + gsz);
  _Float16* ao = (_Float16*)(ws + 2 * gsz);
  _Float16* wb = (_Float16*)(ws + 3 * gsz);

  prep_g_kernel<<<dim3(S_ / 64, B_ * H_), 256, 0, stream>>>(x, theta, kA, vA);
  prep_w_kernel<<<dim3((E_ * E_) / (256 * 8)), 256, 0, stream>>>(W, wb);
  attn_kernel<<<dim3(S_ / 64, B_ * H_), 256, 0, stream>>>(kA, vA, ao);
  proj_kernel<<<dim3((B_ * S_) / 64, E_ / 64), 256, 0, stream>>>(ao, wb, bias, out);
}